// Round 2
// baseline (386.324 us; speedup 1.0000x reference)
//
#include <hip/hip_runtime.h>
#include <cstdint>

// ---------------------------------------------------------------------------
// T-LSTM cell, fp32 in/out, via 3-pass split-bf16 MFMA GEMMs.
// Round 2: fused gates+decomp GEMM dispatch, 32x32x16 MFMA, XOR-swizzled LDS,
// merged prep kernel. 4 dispatches total.
// ---------------------------------------------------------------------------

typedef __attribute__((ext_vector_type(8))) __bf16 bf16x8;
typedef __attribute__((ext_vector_type(16))) float f32x16;

__device__ __forceinline__ unsigned short f2bf_rn(float f) {
  unsigned int u = __float_as_uint(f);
  unsigned int r = u + 0x7fffu + ((u >> 16) & 1u);
  return (unsigned short)(r >> 16);
}
__device__ __forceinline__ float bf2f(unsigned short h) {
  return __uint_as_float(((unsigned int)h) << 16);
}
__device__ __forceinline__ float sigm_f(float x) {
  return 1.0f / (1.0f + __expf(-x));
}
__device__ __forceinline__ float tanh_f(float x) {
  // robust for large |x|: exp overflows to inf -> 1; underflows to 0 -> -1
  return 1.0f - 2.0f / (__expf(2.0f * x) + 1.0f);
}
__device__ __forceinline__ void gl_lds16(const void* g, void* l) {
  __builtin_amdgcn_global_load_lds(
      (const __attribute__((address_space(1))) void*)g,
      (__attribute__((address_space(3))) void*)l, 16, 0, 0);
}

// --- merged prep: split X=[input|hx], W=[W_ih|W_hh], cx into hi/lo bf16.
// 4 fp32 elems per thread, range-dispatched over three regions.
__global__ void prep_k(const float* __restrict__ input, const float* __restrict__ hx,
                       const float* __restrict__ w_ih, const float* __restrict__ w_hh,
                       const float* __restrict__ cx,
                       unsigned short* __restrict__ Xhi, unsigned short* __restrict__ Xlo,
                       unsigned short* __restrict__ Whi, unsigned short* __restrict__ Wlo,
                       unsigned short* __restrict__ Chi, unsigned short* __restrict__ Clo) {
  const long n1 = 4096L * 1536 / 4;  // X region
  const long n2 = 2 * n1;            // + W region
  long idx = blockIdx.x * 256L + threadIdx.x;
  const float* src;
  unsigned short *hi, *lo;
  if (idx < n1) {
    long m = idx / 384;
    int k = (int)(idx % 384) << 2;
    src = (k < 512) ? (input + m * 512 + k) : (hx + m * 1024 + (k - 512));
    hi = Xhi + m * 1536 + k;
    lo = Xlo + m * 1536 + k;
  } else if (idx < n2) {
    long i2 = idx - n1;
    long m = i2 / 384;
    int k = (int)(i2 % 384) << 2;
    src = (k < 512) ? (w_ih + m * 512 + k) : (w_hh + m * 1024 + (k - 512));
    hi = Whi + m * 1536 + k;
    lo = Wlo + m * 1536 + k;
  } else {
    long i3 = idx - n2;
    long m = i3 >> 8;
    int k = ((int)i3 & 255) << 2;
    src = cx + m * 1024 + k;
    hi = Chi + m * 1024 + k;
    lo = Clo + m * 1024 + k;
  }
  float4 v = *(const float4*)src;
  ushort4 hv, lv;
  hv.x = f2bf_rn(v.x); lv.x = f2bf_rn(v.x - bf2f(hv.x));
  hv.y = f2bf_rn(v.y); lv.y = f2bf_rn(v.y - bf2f(hv.y));
  hv.z = f2bf_rn(v.z); lv.z = f2bf_rn(v.z - bf2f(hv.z));
  hv.w = f2bf_rn(v.w); lv.w = f2bf_rn(v.w - bf2f(hv.w));
  *(ushort4*)hi = hv;
  *(ushort4*)lo = lv;
}

// --- transpose-split W_decomp [N,N] fp32 -> T[n][k]=W[k][n] hi/lo bf16
__global__ void transpose_split_k(const float* __restrict__ W, int Ndim,
                                  unsigned short* __restrict__ Thi,
                                  unsigned short* __restrict__ Tlo) {
  __shared__ float tile[64][65];
  const int bx = blockIdx.x * 64;
  const int by = blockIdx.y * 64;
  const int tx = threadIdx.x;
  for (int r = threadIdx.y; r < 64; r += 4)
    tile[r][tx] = W[(long)(by + r) * Ndim + bx + tx];
  __syncthreads();
  for (int r = threadIdx.y; r < 64; r += 4) {
    float v = tile[tx][r];  // = W[by+tx][bx+r]
    unsigned short h = f2bf_rn(v);
    long o = (long)(bx + r) * Ndim + by + tx;
    Thi[o] = h;
    Tlo[o] = f2bf_rn(v - bf2f(h));
  }
}

// --- fused NT GEMM (both problems), C[m,n] = sum_k A[m,k]*B[n,k], 3-pass.
// 128x128 tile, BK=32, 256 threads (4 waves 2x2), 64x64/wave via 2x2 of
// 32x32x16 MFMA. LDS XOR-swizzled: chunk (r,c) lives at slot r*4 + (c^(r&3)).
// blocks [0,256): decomp  (M=4096,N=1024,K=1024) cxadj = cx + (T-1)*tanh(acc+b_d)
// blocks [256,1280): gates (M=4096,N=4096,K=1536) gates = acc + b_ih + b_hh
__global__ __launch_bounds__(256) void gemm_fused(
    const unsigned short* __restrict__ Xh, const unsigned short* __restrict__ Xl,
    const unsigned short* __restrict__ Wh, const unsigned short* __restrict__ Wl,
    const unsigned short* __restrict__ Ch, const unsigned short* __restrict__ Cl,
    const unsigned short* __restrict__ Dh, const unsigned short* __restrict__ Dl,
    float* __restrict__ gates, float* __restrict__ cxadj,
    const float* __restrict__ b_ih, const float* __restrict__ b_hh,
    const float* __restrict__ b_d, const float* __restrict__ cx,
    const float* __restrict__ t) {
  __shared__ __align__(16) unsigned short sAh[128 * 32];
  __shared__ __align__(16) unsigned short sAl[128 * 32];
  __shared__ __align__(16) unsigned short sBh[128 * 32];
  __shared__ __align__(16) unsigned short sBl[128 * 32];

  const bool decomp = (blockIdx.x < 256);
  const unsigned short *Ah, *Al, *Bh, *Bl;
  int N, K, m0, n0;
  if (decomp) {
    Ah = Ch; Al = Cl; Bh = Dh; Bl = Dl;
    N = 1024; K = 1024;
    n0 = (blockIdx.x & 7) * 128;
    m0 = (blockIdx.x >> 3) * 128;
  } else {
    const int bid = blockIdx.x - 256;
    Ah = Xh; Al = Xl; Bh = Wh; Bl = Wl;
    N = 4096; K = 1536;
    n0 = (bid & 31) * 128;
    m0 = (bid >> 5) * 128;
  }

  const int tid = threadIdx.x;
  const int wave = tid >> 6;
  const int lane = tid & 63;
  const int wm = (wave >> 1) * 64;
  const int wn = (wave & 1) * 64;
  // staging: lane L loads row (L>>2), logical chunk (L&3)^((L>>2)&3); HW puts
  // it at LDS slot L -> realizes the XOR swizzle.
  const int srow = lane >> 2;
  const int scol = (((lane & 3) ^ ((lane >> 2) & 3)) << 3);  // bf16 elems
  // fragment indices (32x32x16): A[m=lane&31][k=(lane>>5)*8+j]
  const int lm = lane & 31;
  const int lk = lane >> 5;
  const int lsw = lane & 3;  // == R&3 for all fragment rows (R ≡ lane mod 4)

  f32x16 acc[2][2];
#pragma unroll
  for (int i = 0; i < 2; ++i)
#pragma unroll
    for (int j = 0; j < 2; ++j)
#pragma unroll
      for (int r = 0; r < 16; ++r) acc[i][j][r] = 0.f;

  for (int kt = 0; kt < K; kt += 32) {
#pragma unroll
    for (int r = 0; r < 2; ++r) {
      const int rowb = r * 64 + wave * 16;  // wave-uniform, multiple of 16
      const long gA = (long)(m0 + rowb + srow) * K + kt + scol;
      const long gB = (long)(n0 + rowb + srow) * K + kt + scol;
      const int loff = rowb * 32;  // ushort index
      gl_lds16(Ah + gA, sAh + loff);
      gl_lds16(Al + gA, sAl + loff);
      gl_lds16(Bh + gB, sBh + loff);
      gl_lds16(Bl + gB, sBl + loff);
    }
    __syncthreads();
    // fragment loads: physical chunk = (kh*2 + lk) ^ (R&3), R&3 == lsw
    bf16x8 ah[2][2], al[2][2], bh[2][2], bl[2][2];  // [i|j][kh]
#pragma unroll
    for (int i = 0; i < 2; ++i)
#pragma unroll
      for (int kh = 0; kh < 2; ++kh) {
        const int pc = ((kh * 2 + lk) ^ lsw) << 3;  // bf16 elems within row
        const int ao = (wm + i * 32 + lm) * 32 + pc;
        const int bo = (wn + i * 32 + lm) * 32 + pc;
        ah[i][kh] = *(const bf16x8*)(sAh + ao);
        al[i][kh] = *(const bf16x8*)(sAl + ao);
        bh[i][kh] = *(const bf16x8*)(sBh + bo);
        bl[i][kh] = *(const bf16x8*)(sBl + bo);
      }
#pragma unroll
    for (int kh = 0; kh < 2; ++kh)
#pragma unroll
      for (int i = 0; i < 2; ++i)
#pragma unroll
        for (int j = 0; j < 2; ++j) {
          acc[i][j] = __builtin_amdgcn_mfma_f32_32x32x16_bf16(ah[i][kh], bh[j][kh], acc[i][j], 0, 0, 0);
          acc[i][j] = __builtin_amdgcn_mfma_f32_32x32x16_bf16(ah[i][kh], bl[j][kh], acc[i][j], 0, 0, 0);
          acc[i][j] = __builtin_amdgcn_mfma_f32_32x32x16_bf16(al[i][kh], bh[j][kh], acc[i][j], 0, 0, 0);
        }
    __syncthreads();
  }

  // epilogue: C/D 32x32: col = lane&31, row = (reg&3) + 8*(reg>>2) + 4*(lane>>5)
#pragma unroll
  for (int i = 0; i < 2; ++i) {
#pragma unroll
    for (int j = 0; j < 2; ++j) {
#pragma unroll
      for (int reg = 0; reg < 16; ++reg) {
        const int m = m0 + wm + i * 32 + (reg & 3) + 8 * (reg >> 2) + 4 * lk;
        const int n = n0 + wn + j * 32 + lm;
        const float v = acc[i][j][reg];
        if (!decomp) {
          gates[(long)m * 4096 + n] = v + b_ih[n] + b_hh[n];
        } else {
          const float g = v + b_d[n];
          const float cst = tanh_f(g);
          const float tv = t[m];
          const float T = (tv != 0.0f) ? (1.0f / tv) : 0.0f;
          cxadj[(long)m * 1024 + n] = cx[(long)m * 1024 + n] + (T - 1.0f) * cst;
        }
      }
    }
  }
}

// --- final elementwise: gates [B,4H] + cx_adj [B,H] -> hy, cy
__global__ void final_k(const float* __restrict__ gates,
                        const float* __restrict__ cxadj,
                        float* __restrict__ out) {
  const long idx = blockIdx.x * 256L + threadIdx.x;
  const long m = idx >> 8;
  const int h = ((int)idx & 255) << 2;
  const float4 ig = *(const float4*)(gates + m * 4096 + h);
  const float4 fg = *(const float4*)(gates + m * 4096 + 1024 + h);
  const float4 cg = *(const float4*)(gates + m * 4096 + 2048 + h);
  const float4 og = *(const float4*)(gates + m * 4096 + 3072 + h);
  const float4 ca = *(const float4*)(cxadj + m * 1024 + h);
  const float* igp = (const float*)&ig;
  const float* fgp = (const float*)&fg;
  const float* cgp = (const float*)&cg;
  const float* ogp = (const float*)&og;
  const float* cap = (const float*)&ca;
  float4 hyv, cyv;
  float* hp = (float*)&hyv;
  float* cp = (float*)&cyv;
#pragma unroll
  for (int c = 0; c < 4; ++c) {
    const float cyc = sigm_f(fgp[c]) * cap[c] + sigm_f(igp[c]) * tanh_f(cgp[c]);
    cp[c] = cyc;
    hp[c] = sigm_f(ogp[c]) * tanh_f(cyc);
  }
  *(float4*)(out + m * 1024 + h) = hyv;
  *(float4*)(out + 4096L * 1024 + m * 1024 + h) = cyv;
}

extern "C" void kernel_launch(void* const* d_in, const int* in_sizes, int n_in,
                              void* d_out, int out_size, void* d_ws, size_t ws_size,
                              hipStream_t stream) {
  const float* input = (const float*)d_in[0];
  const float* t     = (const float*)d_in[1];
  const float* hx    = (const float*)d_in[2];
  const float* cx    = (const float*)d_in[3];
  const float* w_ih  = (const float*)d_in[4];
  const float* w_hh  = (const float*)d_in[5];
  const float* b_ih  = (const float*)d_in[6];
  const float* b_hh  = (const float*)d_in[7];
  const float* Wd    = (const float*)d_in[8];
  const float* b_d   = (const float*)d_in[9];

  const long B = 4096, H = 1024, KX = 1536, NG = 4096;

  char* ws = (char*)d_ws;
  unsigned short* Xhi = (unsigned short*)ws; ws += B * KX * 2;
  unsigned short* Xlo = (unsigned short*)ws; ws += B * KX * 2;
  unsigned short* Whi = (unsigned short*)ws; ws += NG * KX * 2;
  unsigned short* Wlo = (unsigned short*)ws; ws += NG * KX * 2;
  unsigned short* Chi = (unsigned short*)ws; ws += B * H * 2;
  unsigned short* Clo = (unsigned short*)ws; ws += B * H * 2;
  unsigned short* Dhi = (unsigned short*)ws; ws += H * H * 2;
  unsigned short* Dlo = (unsigned short*)ws; ws += H * H * 2;
  float* gates = (float*)ws; ws += B * NG * 4;
  float* cxadj = (float*)ws; ws += B * H * 4;

  // 1: all hi/lo splits (X, W, cx) in one range-dispatched kernel
  prep_k<<<16384, 256, 0, stream>>>(input, hx, w_ih, w_hh, cx,
                                    Xhi, Xlo, Whi, Wlo, Chi, Clo);
  // 2: transpose-split W_decomp -> [n][k]
  transpose_split_k<<<dim3(16, 16), dim3(64, 4), 0, stream>>>(Wd, 1024, Dhi, Dlo);
  // 3: fused decomp(256 blocks) + gates(1024 blocks) GEMM
  gemm_fused<<<1280, 256, 0, stream>>>(Xhi, Xlo, Whi, Wlo, Chi, Clo, Dhi, Dlo,
                                       gates, cxadj, b_ih, b_hh, b_d, cx, t);
  // 4: LSTM pointwise -> hy, cy
  final_k<<<4096, 256, 0, stream>>>(gates, cxadj, (float*)d_out);
}

// Round 3
// 384.703 us; speedup vs baseline: 1.0042x; 1.0042x over previous
//
#include <hip/hip_runtime.h>
#include <cstdint>

// ---------------------------------------------------------------------------
// T-LSTM cell, fp32 in/out, via 3-pass split-bf16 MFMA GEMMs.
// Round 3: back to 16x16x32 4x4/wave (R1 structure), CORRECTED xor swizzle
// keyed on (row>>1)&3 (conflict-free for ds_read_b128 8-lane groups),
// single fused GEMM dispatch, division-free prep. 4 dispatches.
// ---------------------------------------------------------------------------

typedef __attribute__((ext_vector_type(8))) __bf16 bf16x8;
typedef __attribute__((ext_vector_type(4))) float f32x4;

__device__ __forceinline__ unsigned short f2bf_rn(float f) {
  unsigned int u = __float_as_uint(f);
  unsigned int r = u + 0x7fffu + ((u >> 16) & 1u);
  return (unsigned short)(r >> 16);
}
__device__ __forceinline__ float bf2f(unsigned short h) {
  return __uint_as_float(((unsigned int)h) << 16);
}
__device__ __forceinline__ float sigm_f(float x) {
  return 1.0f / (1.0f + __expf(-x));
}
__device__ __forceinline__ float tanh_f(float x) {
  return 1.0f - 2.0f / (__expf(2.0f * x) + 1.0f);
}
__device__ __forceinline__ void gl_lds16(const void* g, void* l) {
  __builtin_amdgcn_global_load_lds(
      (const __attribute__((address_space(1))) void*)g,
      (__attribute__((address_space(3))) void*)l, 16, 0, 0);
}

// --- division-free prep: one block per matrix row.
// blocks [0,4096):      X row = [input|hx] -> Xhi/Xlo   (384 thr x 4 elems)
// blocks [4096,8192):   W row = [w_ih|w_hh] -> Whi/Wlo
// blocks [8192,12288):  cx row -> Chi/Clo (256 thr active)
__global__ __launch_bounds__(384) void prep_k(
    const float* __restrict__ input, const float* __restrict__ hx,
    const float* __restrict__ w_ih, const float* __restrict__ w_hh,
    const float* __restrict__ cx,
    unsigned short* __restrict__ Xhi, unsigned short* __restrict__ Xlo,
    unsigned short* __restrict__ Whi, unsigned short* __restrict__ Wlo,
    unsigned short* __restrict__ Chi, unsigned short* __restrict__ Clo) {
  const int bid = blockIdx.x;
  const int k = threadIdx.x << 2;
  const float* src;
  unsigned short *hi, *lo;
  if (bid < 4096) {
    const long m = bid;
    src = (k < 512) ? (input + m * 512 + k) : (hx + m * 1024 + (k - 512));
    hi = Xhi + m * 1536 + k;
    lo = Xlo + m * 1536 + k;
  } else if (bid < 8192) {
    const long m = bid - 4096;
    src = (k < 512) ? (w_ih + m * 512 + k) : (w_hh + m * 1024 + (k - 512));
    hi = Whi + m * 1536 + k;
    lo = Wlo + m * 1536 + k;
  } else {
    if (k >= 1024) return;
    const long m = bid - 8192;
    src = cx + m * 1024 + k;
    hi = Chi + m * 1024 + k;
    lo = Clo + m * 1024 + k;
  }
  float4 v = *(const float4*)src;
  ushort4 hv, lv;
  hv.x = f2bf_rn(v.x); lv.x = f2bf_rn(v.x - bf2f(hv.x));
  hv.y = f2bf_rn(v.y); lv.y = f2bf_rn(v.y - bf2f(hv.y));
  hv.z = f2bf_rn(v.z); lv.z = f2bf_rn(v.z - bf2f(hv.z));
  hv.w = f2bf_rn(v.w); lv.w = f2bf_rn(v.w - bf2f(hv.w));
  *(ushort4*)hi = hv;
  *(ushort4*)lo = lv;
}

// --- transpose-split W_decomp [N,N] fp32 -> T[n][k]=W[k][n] hi/lo bf16
__global__ void transpose_split_k(const float* __restrict__ W, int Ndim,
                                  unsigned short* __restrict__ Thi,
                                  unsigned short* __restrict__ Tlo) {
  __shared__ float tile[64][65];
  const int bx = blockIdx.x * 64;
  const int by = blockIdx.y * 64;
  const int tx = threadIdx.x;
  for (int r = threadIdx.y; r < 64; r += 4)
    tile[r][tx] = W[(long)(by + r) * Ndim + bx + tx];
  __syncthreads();
  for (int r = threadIdx.y; r < 64; r += 4) {
    float v = tile[tx][r];  // = W[by+tx][bx+r]
    unsigned short h = f2bf_rn(v);
    long o = (long)(bx + r) * Ndim + by + tx;
    Thi[o] = h;
    Tlo[o] = f2bf_rn(v - bf2f(h));
  }
}

// --- fused NT GEMM, C[m,n] = sum_k A[m,k]*B[n,k], 3-pass split-bf16.
// 128x128 tile, BK=32, 256 threads (4 waves 2x2), 64x64/wave via 4x4 of
// 16x16x32 MFMA.
// LDS swizzle: physical chunk p of row r holds logical chunk p^((r>>1)&3).
//   - staging: lane L (HW slot: row L>>2, phys chunk L&3) fetches logical
//     chunk (L&3)^((L>>3)&3).
//   - fragment read of logical chunk q at row r uses phys q^((r>>1)&3).
//   Per 8-lane ds_read_b128 group: even rows cover banks 0-15 in 4 distinct
//   quads, odd rows 16-31 -> conflict-free.
// blocks [0,1024):     gates (M=4096,N=4096,K=1536): C = acc + b_ih + b_hh
// blocks [1024,1280):  decomp(M=4096,N=1024,K=1024): cxadj = cx+(T-1)*tanh(acc+b_d)
__global__ __launch_bounds__(256) void gemm_fused(
    const unsigned short* __restrict__ Xh, const unsigned short* __restrict__ Xl,
    const unsigned short* __restrict__ Wh, const unsigned short* __restrict__ Wl,
    const unsigned short* __restrict__ Ch, const unsigned short* __restrict__ Cl,
    const unsigned short* __restrict__ Dh, const unsigned short* __restrict__ Dl,
    float* __restrict__ gates, float* __restrict__ cxadj,
    const float* __restrict__ b_ih, const float* __restrict__ b_hh,
    const float* __restrict__ b_d, const float* __restrict__ cx,
    const float* __restrict__ t) {
  __shared__ __align__(16) unsigned short sAh[128 * 32];
  __shared__ __align__(16) unsigned short sAl[128 * 32];
  __shared__ __align__(16) unsigned short sBh[128 * 32];
  __shared__ __align__(16) unsigned short sBl[128 * 32];

  const bool decomp = (blockIdx.x >= 1024);
  const unsigned short *Ah, *Al, *Bh, *Bl;
  int K, m0, n0;
  if (decomp) {
    const int bid = blockIdx.x - 1024;
    Ah = Ch; Al = Cl; Bh = Dh; Bl = Dl;
    K = 1024;
    n0 = (bid & 7) * 128;
    m0 = (bid >> 3) * 128;
  } else {
    const int bid = blockIdx.x;
    Ah = Xh; Al = Xl; Bh = Wh; Bl = Wl;
    K = 1536;
    n0 = (bid & 31) * 128;
    m0 = (bid >> 5) * 128;
  }

  const int tid = threadIdx.x;
  const int wave = tid >> 6;
  const int lane = tid & 63;
  const int wm = (wave >> 1) * 64;
  const int wn = (wave & 1) * 64;
  // staging indices
  const int srow = lane >> 2;
  const int ssw = (((lane & 3) ^ ((lane >> 3) & 3)) << 3);  // bf16 elems
  // fragment indices (16x16x32): A[m=lane&15][k=(lane>>4)*8+j]
  const int fm = lane & 15;
  const int fq = lane >> 4;
  const int psw = (fq ^ ((fm >> 1) & 3)) << 3;  // swizzled phys chunk, elems

  f32x4 acc[4][4];
#pragma unroll
  for (int i = 0; i < 4; ++i)
#pragma unroll
    for (int j = 0; j < 4; ++j) acc[i][j] = {0.f, 0.f, 0.f, 0.f};

  for (int kt = 0; kt < K; kt += 32) {
#pragma unroll
    for (int r = 0; r < 2; ++r) {
      const int rowb = r * 64 + wave * 16;  // wave-uniform, multiple of 16
      const long gA = (long)(m0 + rowb + srow) * K + kt + ssw;
      const long gB = (long)(n0 + rowb + srow) * K + kt + ssw;
      const int loff = rowb * 32;  // ushort index; HW appends lane*16B
      gl_lds16(Ah + gA, sAh + loff);
      gl_lds16(Al + gA, sAl + loff);
      gl_lds16(Bh + gB, sBh + loff);
      gl_lds16(Bl + gB, sBl + loff);
    }
    __syncthreads();
    bf16x8 ah[4], al[4], bh[4], bl[4];
#pragma unroll
    for (int i = 0; i < 4; ++i) {
      const int ao = (wm + i * 16 + fm) * 32 + psw;
      const int bo = (wn + i * 16 + fm) * 32 + psw;
      ah[i] = *(const bf16x8*)(sAh + ao);
      al[i] = *(const bf16x8*)(sAl + ao);
      bh[i] = *(const bf16x8*)(sBh + bo);
      bl[i] = *(const bf16x8*)(sBl + bo);
    }
#pragma unroll
    for (int i = 0; i < 4; ++i)
#pragma unroll
      for (int j = 0; j < 4; ++j) {
        acc[i][j] = __builtin_amdgcn_mfma_f32_16x16x32_bf16(ah[i], bh[j], acc[i][j], 0, 0, 0);
        acc[i][j] = __builtin_amdgcn_mfma_f32_16x16x32_bf16(ah[i], bl[j], acc[i][j], 0, 0, 0);
        acc[i][j] = __builtin_amdgcn_mfma_f32_16x16x32_bf16(al[i], bh[j], acc[i][j], 0, 0, 0);
      }
    __syncthreads();
  }

  // epilogue: C/D layout col = lane&15, row = (lane>>4)*4 + r  [m89-verified]
#pragma unroll
  for (int i = 0; i < 4; ++i) {
#pragma unroll
    for (int j = 0; j < 4; ++j) {
#pragma unroll
      for (int r = 0; r < 4; ++r) {
        const int m = m0 + wm + i * 16 + fq * 4 + r;
        const int n = n0 + wn + j * 16 + fm;
        const float v = acc[i][j][r];
        if (!decomp) {
          gates[(long)m * 4096 + n] = v + b_ih[n] + b_hh[n];
        } else {
          const float g = v + b_d[n];
          const float cst = tanh_f(g);
          const float tv = t[m];
          const float T = (tv != 0.0f) ? (1.0f / tv) : 0.0f;
          cxadj[(long)m * 1024 + n] = cx[(long)m * 1024 + n] + (T - 1.0f) * cst;
        }
      }
    }
  }
}

// --- final elementwise: gates [B,4H] + cx_adj [B,H] -> hy, cy
__global__ void final_k(const float* __restrict__ gates,
                        const float* __restrict__ cxadj,
                        float* __restrict__ out) {
  const long idx = blockIdx.x * 256L + threadIdx.x;
  const long m = idx >> 8;
  const int h = ((int)idx & 255) << 2;
  const float4 ig = *(const float4*)(gates + m * 4096 + h);
  const float4 fg = *(const float4*)(gates + m * 4096 + 1024 + h);
  const float4 cg = *(const float4*)(gates + m * 4096 + 2048 + h);
  const float4 og = *(const float4*)(gates + m * 4096 + 3072 + h);
  const float4 ca = *(const float4*)(cxadj + m * 1024 + h);
  const float* igp = (const float*)&ig;
  const float* fgp = (const float*)&fg;
  const float* cgp = (const float*)&cg;
  const float* ogp = (const float*)&og;
  const float* cap = (const float*)&ca;
  float4 hyv, cyv;
  float* hp = (float*)&hyv;
  float* cp = (float*)&cyv;
#pragma unroll
  for (int c = 0; c < 4; ++c) {
    const float cyc = sigm_f(fgp[c]) * cap[c] + sigm_f(igp[c]) * tanh_f(cgp[c]);
    cp[c] = cyc;
    hp[c] = sigm_f(ogp[c]) * tanh_f(cyc);
  }
  *(float4*)(out + m * 1024 + h) = hyv;
  *(float4*)(out + 4096L * 1024 + m * 1024 + h) = cyv;
}

extern "C" void kernel_launch(void* const* d_in, const int* in_sizes, int n_in,
                              void* d_out, int out_size, void* d_ws, size_t ws_size,
                              hipStream_t stream) {
  const float* input = (const float*)d_in[0];
  const float* t     = (const float*)d_in[1];
  const float* hx    = (const float*)d_in[2];
  const float* cx    = (const float*)d_in[3];
  const float* w_ih  = (const float*)d_in[4];
  const float* w_hh  = (const float*)d_in[5];
  const float* b_ih  = (const float*)d_in[6];
  const float* b_hh  = (const float*)d_in[7];
  const float* Wd    = (const float*)d_in[8];
  const float* b_d   = (const float*)d_in[9];

  const long B = 4096, H = 1024, KX = 1536, NG = 4096;

  char* ws = (char*)d_ws;
  unsigned short* Xhi = (unsigned short*)ws; ws += B * KX * 2;
  unsigned short* Xlo = (unsigned short*)ws; ws += B * KX * 2;
  unsigned short* Whi = (unsigned short*)ws; ws += NG * KX * 2;
  unsigned short* Wlo = (unsigned short*)ws; ws += NG * KX * 2;
  unsigned short* Chi = (unsigned short*)ws; ws += B * H * 2;
  unsigned short* Clo = (unsigned short*)ws; ws += B * H * 2;
  unsigned short* Dhi = (unsigned short*)ws; ws += H * H * 2;
  unsigned short* Dlo = (unsigned short*)ws; ws += H * H * 2;
  float* gates = (float*)ws; ws += B * NG * 4;
  float* cxadj = (float*)ws; ws += B * H * 4;

  // 1: division-free hi/lo splits (X, W, cx)
  prep_k<<<12288, 384, 0, stream>>>(input, hx, w_ih, w_hh, cx,
                                    Xhi, Xlo, Whi, Wlo, Chi, Clo);
  // 2: transpose-split W_decomp -> [n][k]
  transpose_split_k<<<dim3(16, 16), dim3(64, 4), 0, stream>>>(Wd, 1024, Dhi, Dlo);
  // 3: fused gates(1024 blocks) + decomp(256 blocks) GEMM
  gemm_fused<<<1280, 256, 0, stream>>>(Xhi, Xlo, Whi, Wlo, Chi, Clo, Dhi, Dlo,
                                       gates, cxadj, b_ih, b_hh, b_d, cx, t);
  // 4: LSTM pointwise -> hy, cy
  final_k<<<4096, 256, 0, stream>>>(gates, cxadj, (float*)d_out);
}

// Round 4
// 329.837 us; speedup vs baseline: 1.1713x; 1.1663x over previous
//
#include <hip/hip_runtime.h>
#include <cstdint>

// ---------------------------------------------------------------------------
// T-LSTM cell, fp32 in/out, 3-pass split-bf16 MFMA.
// Round 4: single mega-GEMM. W rows interleaved (n' = (h>>5)*128+g*32+(h&31))
// so each 128-N tile = all 4 gates for a 32-h slice; waves stacked in M
// (32x128/wave) so each thread holds i/f/g/o in registers; decomp GEMM chunk
// (128m x 32h x 1024k) fused into the same block; epilogue computes cy/hy
// directly. 3 dispatches: prep, transpose, mega.
// ---------------------------------------------------------------------------

typedef __attribute__((ext_vector_type(8))) __bf16 bf16x8;
typedef __attribute__((ext_vector_type(4))) float f32x4;

__device__ __forceinline__ unsigned short f2bf_rn(float f) {
  unsigned int u = __float_as_uint(f);
  unsigned int r = u + 0x7fffu + ((u >> 16) & 1u);
  return (unsigned short)(r >> 16);
}
__device__ __forceinline__ float bf2f(unsigned short h) {
  return __uint_as_float(((unsigned int)h) << 16);
}
__device__ __forceinline__ float sigm_f(float x) {
  return 1.0f / (1.0f + __expf(-x));
}
__device__ __forceinline__ float tanh_f(float x) {
  return 1.0f - 2.0f / (__expf(2.0f * x) + 1.0f);
}
__device__ __forceinline__ void gl_lds16(const void* g, void* l) {
  __builtin_amdgcn_global_load_lds(
      (const __attribute__((address_space(1))) void*)g,
      (__attribute__((address_space(3))) void*)l, 16, 0, 0);
}

// --- prep: split X=[input|hx], W=[w_ih|w_hh] (rows gate-interleaved), cx.
// blocks [0,4096): X row m          (384 thr x 4)
// blocks [4096,8192): W source row n -> dest row (h>>5)*128+g*32+(h&31)
// blocks [8192,12288): cx row       (256 thr active)
__global__ __launch_bounds__(384) void prep_k(
    const float* __restrict__ input, const float* __restrict__ hx,
    const float* __restrict__ w_ih, const float* __restrict__ w_hh,
    const float* __restrict__ cx,
    unsigned short* __restrict__ Xhi, unsigned short* __restrict__ Xlo,
    unsigned short* __restrict__ Whi, unsigned short* __restrict__ Wlo,
    unsigned short* __restrict__ Chi, unsigned short* __restrict__ Clo) {
  const int bid = blockIdx.x;
  const int k = threadIdx.x << 2;
  const float* src;
  unsigned short *hi, *lo;
  if (bid < 4096) {
    const long m = bid;
    src = (k < 512) ? (input + m * 512 + k) : (hx + m * 1024 + (k - 512));
    hi = Xhi + m * 1536 + k;
    lo = Xlo + m * 1536 + k;
  } else if (bid < 8192) {
    const int n = bid - 4096;
    const int g = n >> 10;
    const int h = n & 1023;
    const long nd = ((h >> 5) << 7) | (g << 5) | (h & 31);  // interleaved row
    src = (k < 512) ? (w_ih + (long)n * 512 + k) : (w_hh + (long)n * 1024 + (k - 512));
    hi = Whi + nd * 1536 + k;
    lo = Wlo + nd * 1536 + k;
  } else {
    if (k >= 1024) return;
    const long m = bid - 8192;
    src = cx + m * 1024 + k;
    hi = Chi + m * 1024 + k;
    lo = Clo + m * 1024 + k;
  }
  float4 v = *(const float4*)src;
  ushort4 hv, lv;
  hv.x = f2bf_rn(v.x); lv.x = f2bf_rn(v.x - bf2f(hv.x));
  hv.y = f2bf_rn(v.y); lv.y = f2bf_rn(v.y - bf2f(hv.y));
  hv.z = f2bf_rn(v.z); lv.z = f2bf_rn(v.z - bf2f(hv.z));
  hv.w = f2bf_rn(v.w); lv.w = f2bf_rn(v.w - bf2f(hv.w));
  *(ushort4*)hi = hv;
  *(ushort4*)lo = lv;
}

// --- transpose-split W_decomp [K,H] fp32 -> D[h][k]=W[k][h] hi/lo bf16
__global__ void transpose_split_k(const float* __restrict__ W, int Ndim,
                                  unsigned short* __restrict__ Thi,
                                  unsigned short* __restrict__ Tlo) {
  __shared__ float tile[64][65];
  const int bx = blockIdx.x * 64;
  const int by = blockIdx.y * 64;
  const int tx = threadIdx.x;
  for (int r = threadIdx.y; r < 64; r += 4)
    tile[r][tx] = W[(long)(by + r) * Ndim + bx + tx];
  __syncthreads();
  for (int r = threadIdx.y; r < 64; r += 4) {
    float v = tile[tx][r];  // = W[by+tx][bx+r]
    unsigned short h = f2bf_rn(v);
    long o = (long)(bx + r) * Ndim + by + tx;
    Thi[o] = h;
    Tlo[o] = f2bf_rn(v - bf2f(h));
  }
}

// --- mega kernel: per block (m_blk, n_blk):
//   phase 1: dacc[2][2] = cx[m-range128] @ D[h-range32]^T  (K=1024)
//   phase 2: acc[2][8]  = X[m-range128]  @ W'[n-range128]^T (K=1536)
//   epilogue: full T-LSTM pointwise -> hy, cy (direct to out)
// 256 thr, 4 waves stacked in M (32 rows x 128 cols each).
// LDS swizzle (R3-verified, 0 conflicts): phys chunk p of row r holds logical
// chunk p^((r>>1)&3); staging lane L fetches logical (L&3)^((L>>3)&3).
__global__ __launch_bounds__(256) void gemm_mega(
    const unsigned short* __restrict__ Xh, const unsigned short* __restrict__ Xl,
    const unsigned short* __restrict__ Wh, const unsigned short* __restrict__ Wl,
    const unsigned short* __restrict__ Ch, const unsigned short* __restrict__ Cl,
    const unsigned short* __restrict__ Dh, const unsigned short* __restrict__ Dl,
    const float* __restrict__ b_ih, const float* __restrict__ b_hh,
    const float* __restrict__ b_d, const float* __restrict__ cx,
    const float* __restrict__ t, float* __restrict__ out) {
  __shared__ __align__(16) unsigned short sAh[128 * 32];
  __shared__ __align__(16) unsigned short sAl[128 * 32];
  __shared__ __align__(16) unsigned short sBh[128 * 32];
  __shared__ __align__(16) unsigned short sBl[128 * 32];

  const int n_blk = blockIdx.x & 31;
  const int m_blk = blockIdx.x >> 5;
  const int m0 = m_blk * 128;
  const int n0 = n_blk * 128;   // interleaved-W row offset
  const int h0 = n_blk * 32;    // global h offset of this block

  const int tid = threadIdx.x;
  const int wave = tid >> 6;
  const int lane = tid & 63;
  const int srow = lane >> 2;
  const int ssw = (((lane & 3) ^ ((lane >> 3) & 3)) << 3);  // bf16 elems
  const int fm = lane & 15;
  const int fq = lane >> 4;
  const int psw = (fq ^ ((fm >> 1) & 3)) << 3;

  // ---------------- phase 1: decomp  dacc = cx @ D^T ----------------
  f32x4 dacc[2][2];
#pragma unroll
  for (int i = 0; i < 2; ++i)
#pragma unroll
    for (int j = 0; j < 2; ++j) dacc[i][j] = {0.f, 0.f, 0.f, 0.f};

  {
    // B staging assignment: wave0->sBh rows 0-15, wave1->sBh 16-31,
    // wave2->sBl 0-15, wave3->sBl 16-31
    const unsigned short* dsrc = (wave < 2) ? Dh : Dl;
    unsigned short* ddst = ((wave < 2) ? sBh : sBl) + ((wave & 1) * 16) * 32;
    const long dgbase = (long)(h0 + (wave & 1) * 16 + srow) * 1024 + ssw;
    for (int kt = 0; kt < 1024; kt += 32) {
#pragma unroll
      for (int r = 0; r < 2; ++r) {
        const int rowb = r * 64 + wave * 16;
        const long gA = (long)(m0 + rowb + srow) * 1024 + kt + ssw;
        gl_lds16(Ch + gA, sAh + rowb * 32);
        gl_lds16(Cl + gA, sAl + rowb * 32);
      }
      gl_lds16(dsrc + dgbase + kt, ddst);
      __syncthreads();
      bf16x8 ah[2], al[2], bh[2], bl[2];
#pragma unroll
      for (int i = 0; i < 2; ++i) {
        const int ao = (wave * 32 + i * 16 + fm) * 32 + psw;
        ah[i] = *(const bf16x8*)(sAh + ao);
        al[i] = *(const bf16x8*)(sAl + ao);
        const int bo = (i * 16 + fm) * 32 + psw;
        bh[i] = *(const bf16x8*)(sBh + bo);
        bl[i] = *(const bf16x8*)(sBl + bo);
      }
#pragma unroll
      for (int i = 0; i < 2; ++i)
#pragma unroll
        for (int j = 0; j < 2; ++j) {
          dacc[i][j] = __builtin_amdgcn_mfma_f32_16x16x32_bf16(ah[i], bh[j], dacc[i][j], 0, 0, 0);
          dacc[i][j] = __builtin_amdgcn_mfma_f32_16x16x32_bf16(ah[i], bl[j], dacc[i][j], 0, 0, 0);
          dacc[i][j] = __builtin_amdgcn_mfma_f32_16x16x32_bf16(al[i], bh[j], dacc[i][j], 0, 0, 0);
        }
      __syncthreads();
    }
  }

  // ---------------- phase 2: gates  acc = X @ W'^T ----------------
  f32x4 acc[2][8];
#pragma unroll
  for (int i = 0; i < 2; ++i)
#pragma unroll
    for (int j = 0; j < 8; ++j) acc[i][j] = {0.f, 0.f, 0.f, 0.f};

  for (int kt = 0; kt < 1536; kt += 32) {
#pragma unroll
    for (int r = 0; r < 2; ++r) {
      const int rowb = r * 64 + wave * 16;
      const long gA = (long)(m0 + rowb + srow) * 1536 + kt + ssw;
      const long gB = (long)(n0 + rowb + srow) * 1536 + kt + ssw;
      gl_lds16(Xh + gA, sAh + rowb * 32);
      gl_lds16(Xl + gA, sAl + rowb * 32);
      gl_lds16(Wh + gB, sBh + rowb * 32);
      gl_lds16(Wl + gB, sBl + rowb * 32);
    }
    __syncthreads();
    bf16x8 ah[2], al[2];
#pragma unroll
    for (int i = 0; i < 2; ++i) {
      const int ao = (wave * 32 + i * 16 + fm) * 32 + psw;
      ah[i] = *(const bf16x8*)(sAh + ao);
      al[i] = *(const bf16x8*)(sAl + ao);
    }
#pragma unroll
    for (int jh = 0; jh < 2; ++jh) {
      bf16x8 bh[4], bl[4];
#pragma unroll
      for (int jj = 0; jj < 4; ++jj) {
        const int bo = ((jh * 4 + jj) * 16 + fm) * 32 + psw;
        bh[jj] = *(const bf16x8*)(sBh + bo);
        bl[jj] = *(const bf16x8*)(sBl + bo);
      }
#pragma unroll
      for (int i = 0; i < 2; ++i)
#pragma unroll
        for (int jj = 0; jj < 4; ++jj) {
          const int j = jh * 4 + jj;
          acc[i][j] = __builtin_amdgcn_mfma_f32_16x16x32_bf16(ah[i], bh[jj], acc[i][j], 0, 0, 0);
          acc[i][j] = __builtin_amdgcn_mfma_f32_16x16x32_bf16(ah[i], bl[jj], acc[i][j], 0, 0, 0);
          acc[i][j] = __builtin_amdgcn_mfma_f32_16x16x32_bf16(al[i], bh[jj], acc[i][j], 0, 0, 0);
        }
    }
    __syncthreads();
  }

  // ---------------- epilogue: full T-LSTM pointwise ----------------
  // thread's outputs: m = m0 + wave*32 + i*16 + fq*4 + r ; h = h0 + j0*16 + fm
  // gate g value at acc[i][g*2+j0][r]
#pragma unroll
  for (int j0 = 0; j0 < 2; ++j0) {
    const int h = h0 + j0 * 16 + fm;
    const float bsum_i = b_ih[h]           + b_hh[h];
    const float bsum_f = b_ih[1024 + h]    + b_hh[1024 + h];
    const float bsum_g = b_ih[2048 + h]    + b_hh[2048 + h];
    const float bsum_o = b_ih[3072 + h]    + b_hh[3072 + h];
    const float bd = b_d[h];
#pragma unroll
    for (int i = 0; i < 2; ++i) {
#pragma unroll
      for (int r = 0; r < 4; ++r) {
        const int m = m0 + wave * 32 + i * 16 + fq * 4 + r;
        const float tv = t[m];
        const float T = (tv != 0.0f) ? (1.0f / tv) : 0.0f;
        const float cst = tanh_f(dacc[i][j0][r] + bd);
        const float cadj = cx[(long)m * 1024 + h] + (T - 1.0f) * cst;
        const float ig = sigm_f(acc[i][0 + j0][r] + bsum_i);
        const float fg = sigm_f(acc[i][2 + j0][r] + bsum_f);
        const float cg = tanh_f(acc[i][4 + j0][r] + bsum_g);
        const float og = sigm_f(acc[i][6 + j0][r] + bsum_o);
        const float cy = fg * cadj + ig * cg;
        const float hy = og * tanh_f(cy);
        out[(long)m * 1024 + h] = hy;
        out[4096L * 1024 + (long)m * 1024 + h] = cy;
      }
    }
  }
}

extern "C" void kernel_launch(void* const* d_in, const int* in_sizes, int n_in,
                              void* d_out, int out_size, void* d_ws, size_t ws_size,
                              hipStream_t stream) {
  const float* input = (const float*)d_in[0];
  const float* t     = (const float*)d_in[1];
  const float* hx    = (const float*)d_in[2];
  const float* cx    = (const float*)d_in[3];
  const float* w_ih  = (const float*)d_in[4];
  const float* w_hh  = (const float*)d_in[5];
  const float* b_ih  = (const float*)d_in[6];
  const float* b_hh  = (const float*)d_in[7];
  const float* Wd    = (const float*)d_in[8];
  const float* b_d   = (const float*)d_in[9];

  const long B = 4096, H = 1024, KX = 1536, NG = 4096;

  char* ws = (char*)d_ws;
  unsigned short* Xhi = (unsigned short*)ws; ws += B * KX * 2;
  unsigned short* Xlo = (unsigned short*)ws; ws += B * KX * 2;
  unsigned short* Whi = (unsigned short*)ws; ws += NG * KX * 2;
  unsigned short* Wlo = (unsigned short*)ws; ws += NG * KX * 2;
  unsigned short* Chi = (unsigned short*)ws; ws += B * H * 2;
  unsigned short* Clo = (unsigned short*)ws; ws += B * H * 2;
  unsigned short* Dhi = (unsigned short*)ws; ws += H * H * 2;
  unsigned short* Dlo = (unsigned short*)ws; ws += H * H * 2;

  // 1: hi/lo splits (X, W gate-interleaved, cx)
  prep_k<<<12288, 384, 0, stream>>>(input, hx, w_ih, w_hh, cx,
                                    Xhi, Xlo, Whi, Wlo, Chi, Clo);
  // 2: transpose-split W_decomp -> D[h][k]
  transpose_split_k<<<dim3(16, 16), dim3(64, 4), 0, stream>>>(Wd, 1024, Dhi, Dlo);
  // 3: mega GEMM (decomp + gates + full pointwise epilogue)
  gemm_mega<<<1024, 256, 0, stream>>>(Xhi, Xlo, Whi, Wlo, Chi, Clo, Dhi, Dlo,
                                      b_ih, b_hh, b_d, cx, t, (float*)d_out);
}